// Round 1
// baseline (149.706 us; speedup 1.0000x reference)
//
#include <hip/hip_runtime.h>

// inside[b,p] = c00*dx0^2 + c11*dx1^2 + 2*c01*dx0*dx1
// dx0 = z0^2*tx - z0*mx ; dx1 = z0^2*ty - z0*my
// Per-Gaussian scalars computed once per block by lane 0 into LDS.

__global__ __launch_bounds__(256) void splat_quadratic_kernel(
    const float* __restrict__ means_hom,   // 4
    const float* __restrict__ x,           // B*16  (B,4,4) row-major
    const float* __restrict__ cov_world,   // 9     (3,3)
    const float* __restrict__ tile_coord,  // P*2   (P,2)
    float* __restrict__ out,               // B*P
    int P)
{
    __shared__ float s[6]; // conic00, conic01, conic11, z2, z0mx, z0my

    const int b = blockIdx.x;

    if (threadIdx.x == 0) {
        const float* xb = x + (size_t)b * 16;
        const float m0 = means_hom[0], m1 = means_hom[1];
        const float m2 = means_hom[2], m3 = means_hom[3];

        // means_cam[j] = dot(x[b] row j, m), j=0..2
        const float xm = xb[0] * m0 + xb[1] * m1 + xb[2]  * m2 + xb[3]  * m3;
        const float ym = xb[4] * m0 + xb[5] * m1 + xb[6]  * m2 + xb[7]  * m3;
        const float zc = xb[8] * m0 + xb[9] * m1 + xb[10] * m2 + xb[11] * m3;

        const float FX = 2343.0242837919386f;
        const float FY = 2343.0242837919386f;
        const float CX = 1280.0f; // W/2
        const float CY = 720.0f;  // H/2

        // means2D (pre-division projective coords) and z0
        const float mx = FX * xm + CX * zc;
        const float my = FY * ym + CY * zc;
        const float z0 = zc;

        // R_cam = x[:3,:3]
        float R[3][3] = {{xb[0], xb[1], xb[2]},
                         {xb[4], xb[5], xb[6]},
                         {xb[8], xb[9], xb[10]}};
        float Cw[3][3] = {{cov_world[0], cov_world[1], cov_world[2]},
                          {cov_world[3], cov_world[4], cov_world[5]},
                          {cov_world[6], cov_world[7], cov_world[8]}};

        // M = R * Cw ; cov_cam = M * R^T
        float M[3][3];
        #pragma unroll
        for (int i = 0; i < 3; ++i)
            #pragma unroll
            for (int j = 0; j < 3; ++j)
                M[i][j] = R[i][0] * Cw[0][j] + R[i][1] * Cw[1][j] + R[i][2] * Cw[2][j];

        float cc[3][3];
        #pragma unroll
        for (int i = 0; i < 3; ++i)
            #pragma unroll
            for (int j = 0; j < 3; ++j)
                cc[i][j] = M[i][0] * R[j][0] + M[i][1] * R[j][1] + M[i][2] * R[j][2];

        const float c00 = cc[0][0], c01 = cc[0][1], c02 = cc[0][2];
        const float c11 = cc[1][1], c12 = cc[1][2];
        const float c20 = cc[2][0], c21 = cc[2][1], c22 = cc[2][2];

        const float J00 = zc * FX;
        const float J02 = -FX * xm;
        const float J11 = zc * FY;
        const float J12 = -FY * ym;

        const float a  = J00 * J00 * c00 + J00 * J02 * c02 + J02 * J00 * c20 + J02 * J02 * c22;
        const float d  = J11 * J11 * c11 + J11 * J12 * c12 + J12 * J11 * c21 + J12 * J12 * c22;
        const float bb = J00 * J11 * c01 + J00 * J12 * c02 + J02 * J11 * c21 + J02 * J12 * c22;

        const float det = a * d - bb * bb;
        const float inv = 1.0f / det;

        s[0] = d * inv;    // conic00
        s[1] = -bb * inv;  // conic01
        s[2] = a * inv;    // conic11
        s[3] = z0 * z0;    // z2
        s[4] = z0 * mx;    // z0*means2D.x
        s[5] = z0 * my;    // z0*means2D.y
    }
    __syncthreads();

    const float conic00 = s[0];
    const float conic01 = s[1];
    const float conic11 = s[2];
    const float z2   = s[3];
    const float z0mx = s[4];
    const float z0my = s[5];

    const float4* __restrict__ tc4 = (const float4*)tile_coord;
    float4* __restrict__ out4 = (float4*)(out + (size_t)b * P);

    // Each iteration handles 4 pixels: 2 float4 tile loads, 1 float4 store.
    for (int p = threadIdx.x * 4; p < P; p += blockDim.x * 4) {
        const float4 t0 = tc4[p >> 1];       // tx0 ty0 tx1 ty1
        const float4 t1 = tc4[(p >> 1) + 1]; // tx2 ty2 tx3 ty3

        float4 r;
        {
            const float dx = z2 * t0.x - z0mx;
            const float dy = z2 * t0.y - z0my;
            r.x = dx * dx * conic00 + dy * dy * conic11 + 2.0f * dx * dy * conic01;
        }
        {
            const float dx = z2 * t0.z - z0mx;
            const float dy = z2 * t0.w - z0my;
            r.y = dx * dx * conic00 + dy * dy * conic11 + 2.0f * dx * dy * conic01;
        }
        {
            const float dx = z2 * t1.x - z0mx;
            const float dy = z2 * t1.y - z0my;
            r.z = dx * dx * conic00 + dy * dy * conic11 + 2.0f * dx * dy * conic01;
        }
        {
            const float dx = z2 * t1.z - z0mx;
            const float dy = z2 * t1.w - z0my;
            r.w = dx * dx * conic00 + dy * dy * conic11 + 2.0f * dx * dy * conic01;
        }
        out4[p >> 2] = r;
    }
}

extern "C" void kernel_launch(void* const* d_in, const int* in_sizes, int n_in,
                              void* d_out, int out_size, void* d_ws, size_t ws_size,
                              hipStream_t stream) {
    const float* means_hom  = (const float*)d_in[0]; // 4
    const float* x          = (const float*)d_in[1]; // B*16
    const float* cov_world  = (const float*)d_in[2]; // 9
    // d_in[3] = opacities_rast (unused by reference output)
    const float* tile_coord = (const float*)d_in[4]; // P*2

    const int B = in_sizes[1] / 16;
    const int P = in_sizes[4] / 2;

    float* out = (float*)d_out;

    splat_quadratic_kernel<<<B, 256, 0, stream>>>(
        means_hom, x, cov_world, tile_coord, out, P);
}